// Round 6
// baseline (1166.306 us; speedup 1.0000x reference)
//
#include <hip/hip_runtime.h>

#define TT 500
typedef __attribute__((ext_vector_type(8))) short short8v;
typedef __attribute__((ext_vector_type(4))) short short4v;
typedef __attribute__((ext_vector_type(4))) float float4v;
typedef unsigned short ushort;

__device__ __forceinline__ ushort f2bf(float f) {
  union { float f; unsigned u; } v; v.f = f;
  unsigned r = v.u + 0x7FFFu + ((v.u >> 16) & 1u);
  return (ushort)(r >> 16);
}
__device__ __forceinline__ float bf2f(ushort u) {
  union { unsigned u; float f; } v; v.u = ((unsigned)u) << 16;
  return v.f;
}
__device__ __forceinline__ float sigm(float x) {
  return __builtin_amdgcn_rcpf(1.f + __builtin_amdgcn_exp2f(-1.44269504088896341f * x));
}
__device__ __forceinline__ float tanh_f(float x) {
  return 1.f - 2.f * __builtin_amdgcn_rcpf(1.f + __builtin_amdgcn_exp2f(2.88539008177792682f * x));
}
// LDS-only barrier: does NOT drain vmcnt -> global prefetches stay in flight.
__device__ __forceinline__ void bar_lds() {
  asm volatile("s_waitcnt lgkmcnt(0)\ns_barrier" ::: "memory");
}
template <int CTRL>
__device__ __forceinline__ float dppadd(float v) {
  int a = __builtin_amdgcn_update_dpp(0, __builtin_bit_cast(int, v), CTRL, 0xF, 0xF, true);
  return v + __builtin_bit_cast(float, a);
}
__device__ __forceinline__ float rsum16(float v) {  // sum over 16-lane row
  v = dppadd<0xB1>(v);
  v = dppadd<0x4E>(v);
  v = dppadd<0x141>(v);  // row_half_mirror
  v = dppadd<0x140>(v);  // row_mirror
  return v;
}

// ---------------------------------------------------------------------------
// phase0: weights -> bf16
// ---------------------------------------------------------------------------
__global__ __launch_bounds__(256) void conv_k(
    const float* __restrict__ W1, const float* __restrict__ W2,
    const float* __restrict__ W3, const float* __restrict__ Wih,
    const float* __restrict__ key, const float* __restrict__ Wg,
    const float* __restrict__ Wgg, ushort* __restrict__ wts)
{
  int idx = blockIdx.x * 256 + threadIdx.x;
  if (idx >= 200704) return;
  float v;
  if (idx < 32768)       v = W1[idx];
  else if (idx < 81920)  v = W2[idx - 32768];
  else if (idx < 114688) v = W3[idx - 81920];
  else if (idx < 163840) v = Wih[idx - 114688];
  else if (idx < 167936) v = key[idx - 163840];
  else {
    int j = idx - 167936, o = j >> 7, k = j & 127;
    v = (o < 128) ? Wg[o * 256 + 128 + k] : Wgg[(o - 128) * 256 + 128 + k];
  }
  wts[idx] = f2bf(v);
}

// ---------------------------------------------------------------------------
// phase1: token-parallel precompute. LDS overlaid (Xl|Yl then St) for occupancy.
// ---------------------------------------------------------------------------
#define XS 424
#define SS 648

__global__ __launch_bounds__(256, 4) void phase1_k(
    const int* __restrict__ a_data, const int* __restrict__ e_data,
    const float* __restrict__ qm, const float* __restrict__ semb,
    const float* __restrict__ aemb, const float* __restrict__ eemb,
    const float* __restrict__ b1, const float* __restrict__ b2,
    const float* __restrict__ b3, const float* __restrict__ bih,
    const float* __restrict__ bg, const float* __restrict__ bgg,
    const float* __restrict__ Wp, const float* __restrict__ bp,
    const float* __restrict__ Wp1, const float* __restrict__ bp1,
    const ushort* __restrict__ wts,
    ushort* __restrict__ gxb, ushort* __restrict__ xgx,
    float* __restrict__ wallb, float* __restrict__ c1b, float* __restrict__ c2b)
{
  __shared__ __align__(16) ushort sbuf[13568];   // 27,136 B total
  ushort* Xl = sbuf;              // 16*424
  ushort* Yl = sbuf + 6784;       // 16*424
  ushort* St = sbuf;              // 16*648 (overlays Xl+Yl, used after both die)
  const int tid = threadIdx.x;
  const int b = blockIdx.x >> 5, chunk = blockIdx.x & 31;
  const int t0 = chunk * 16;
  const int NT = (TT - t0 < 16) ? (TT - t0) : 16;
  const ushort* w1b  = wts;
  const ushort* w2b  = wts + 32768;
  const ushort* w3b  = wts + 81920;
  const ushort* wihb = wts + 114688;
  const ushort* keyb = wts + 163840;
  const ushort* wgb  = wts + 167936;

  // ---- stage 0: X via ballot-compressed sparse gather
  {
    const int tok = tid >> 4, l16 = tid & 15;
    const int tsrc = (tok < NT) ? tok : (NT - 1);
    const int gt = b * TT + t0 + tsrc;
    const int e = e_data[gt], a = a_data[gt];
    const float* qrow = qm + (size_t)e * 101;
    float qv[7];
#pragma unroll
    for (int i = 0; i < 7; ++i) {
      int s = l16 + 16 * i;
      qv[i] = (s < 101) ? qrow[s] : 0.f;
    }
    const float* sbase = semb + l16 * 8;
    float4v acc0 = {0,0,0,0}, acc1 = {0,0,0,0};
    float cnt = 0.f;
#pragma unroll
    for (int i = 0; i < 7; ++i) {
      unsigned long long bal = __ballot(qv[i] != 0.f);
      unsigned m = (unsigned)((bal >> (tid & 48)) & 0xFFFFull);
      cnt += (float)__popc(m);
      while (m) {
        int s = 16 * i + __builtin_ctz(m);
        m &= m - 1;
        acc0 += *(const float4v*)(sbase + s * 128);
        acc1 += *(const float4v*)(sbase + s * 128 + 4);
      }
    }
    float inv = 1.f / fmaxf(cnt, 1.f);
    ushort* xr = Xl + tok * XS + l16 * 8;
#pragma unroll
    for (int r = 0; r < 4; ++r) { xr[r] = f2bf(acc0[r] * inv); xr[4 + r] = f2bf(acc1[r] * inv); }
    const float* ee = eemb + (size_t)e * 128 + l16 * 8;
    const float* ae = aemb + a * 128 + l16 * 8;
    ushort* xe = Xl + tok * XS + 128 + l16 * 8;
    ushort* xa = Xl + tok * XS + 256 + l16 * 8;
#pragma unroll
    for (int r = 0; r < 8; ++r) { xe[r] = f2bf(ee[r]); xa[r] = f2bf(ae[r]); }
  }
  __syncthreads();

  const int w = tid >> 6, l = tid & 63, jj = l & 15, seg = l >> 4;

  // ---- c1 (reads Xl e_emb part)
  if (tid < 16) {
    int tau = tid;
    if (tau < NT) {
      const ushort* xr = Xl + tau * XS + 128;
      const float* wv = Wp + 256;
      float a0 = bp[0], a1 = 0.f, a2 = 0.f, a3 = 0.f;
      for (int j = 0; j < 128; j += 4) {
        a0 = fmaf(wv[j],     bf2f(xr[j]),     a0);
        a1 = fmaf(wv[j + 1], bf2f(xr[j + 1]), a1);
        a2 = fmaf(wv[j + 2], bf2f(xr[j + 2]), a2);
        a3 = fmaf(wv[j + 3], bf2f(xr[j + 3]), a3);
      }
      c1b[b * TT + t0 + tau] = (a0 + a1) + (a2 + a3);
    }
  }

  // ---- stage A: Y via MFMA
  short8v ax[12];
#pragma unroll
  for (int i = 0; i < 12; ++i)
    ax[i] = *(short8v*)(Xl + jj * XS + i * 32 + seg * 8);

  for (int T = w; T < 24; T += 4) {
    float4v d = {0,0,0,0};
    float bv;
    if (T < 8) {
      const ushort* Bp = w1b + (T * 16 + jj) * 256 + seg * 8;
      bv = b1[T * 16 + jj];
#pragma unroll
      for (int k = 0; k < 8; ++k)
        d = __builtin_amdgcn_mfma_f32_16x16x32_bf16(ax[k], *(const short8v*)(Bp + k * 32), d, 0, 0, 0);
    } else if (T < 16) {
      const ushort* Bp = w2b + ((T - 8) * 16 + jj) * 384 + seg * 8;
      bv = b2[(T - 8) * 16 + jj];
#pragma unroll
      for (int k = 0; k < 12; ++k)
        d = __builtin_amdgcn_mfma_f32_16x16x32_bf16(ax[k], *(const short8v*)(Bp + k * 32), d, 0, 0, 0);
    } else {
      const ushort* Bp = w3b + ((T - 16) * 16 + jj) * 256 + seg * 8;
      bv = b3[(T - 16) * 16 + jj];
#pragma unroll
      for (int k = 0; k < 8; ++k)
        d = __builtin_amdgcn_mfma_f32_16x16x32_bf16(ax[4 + k], *(const short8v*)(Bp + k * 32), d, 0, 0, 0);
    }
#pragma unroll
    for (int r = 0; r < 4; ++r) {
      float y = d[r] + bv;
      Yl[(seg * 4 + r) * XS + T * 16 + jj] = f2bf(y > 0.f ? y : 0.f);
    }
  }
  __syncthreads();

  // ---- load ay regs + c2 (reads Yl se_data part)
  short8v ay[12];
#pragma unroll
  for (int i = 0; i < 12; ++i)
    ay[i] = *(short8v*)(Yl + jj * XS + i * 32 + seg * 8);

  if (tid < 16) {
    int tau = tid;
    if (tau < NT) {
      const ushort* xr = Yl + tau * XS;
      const float* wv = Wp1 + 256;
      float a0 = bp1[0], a1 = 0.f, a2 = 0.f, a3 = 0.f;
      for (int j = 0; j < 128; j += 4) {
        a0 = fmaf(wv[j],     bf2f(xr[j]),     a0);
        a1 = fmaf(wv[j + 1], bf2f(xr[j + 1]), a1);
        a2 = fmaf(wv[j + 2], bf2f(xr[j + 2]), a2);
        a3 = fmaf(wv[j + 3], bf2f(xr[j + 3]), a3);
      }
      c2b[b * TT + t0 + tau] = (a0 + a1) + (a2 + a3);
    }
  }

  // ---- stage B MFMAs (registers only)
  float4v ds[11];
  int nst = 0;
  for (int T = w; T < 42; T += 4, ++nst) {
    const ushort* Bp; int ai;
    if (T < 24)      { Bp = wihb + (T * 16 + jj) * 128 + seg * 8;        ai = 8; }
    else if (T < 40) { Bp = wgb  + ((T - 24) * 16 + jj) * 128 + seg * 8; ai = 4; }
    else             { Bp = keyb + ((T - 40) * 16 + jj) * 128 + seg * 8; ai = 0; }
    float4v d = {0,0,0,0};
#pragma unroll
    for (int k = 0; k < 4; ++k)
      d = __builtin_amdgcn_mfma_f32_16x16x32_bf16(ay[ai + k], *(const short8v*)(Bp + k * 32), d, 0, 0, 0);
    ds[nst] = d;
  }
  __syncthreads();   // Xl/Yl dead; St may now overlay

  nst = 0;
  for (int T = w; T < 42; T += 4, ++nst) {
    float4v d = ds[nst];
    if (T < 40) {
      float bv = (T < 24) ? bih[T * 16 + jj]
               : (T < 32) ? bg[(T - 24) * 16 + jj] : bgg[(T - 32) * 16 + jj];
      int col = (T < 24) ? (T * 16 + jj) : (384 + (T - 24) * 16 + jj);
#pragma unroll
      for (int r = 0; r < 4; ++r)
        St[(seg * 4 + r) * SS + col] = f2bf(d[r] + bv);
    } else {
#pragma unroll
      for (int r = 0; r < 4; ++r) {
        int tok = seg * 4 + r;
        if (tok < NT)
          wallb[((size_t)(b * TT + t0 + tok)) * 32 + (T - 40) * 16 + jj] = d[r];
      }
    }
  }
  __syncthreads();

  // ---- coalesced copy-out
  {
    const int tok = tid >> 4, sg = tid & 15;
    if (tok < NT) {
      size_t gt = (size_t)b * TT + t0 + tok;
#pragma unroll
      for (int p = 0; p < 3; ++p)
        *(short8v*)(gxb + gt * 384 + sg * 24 + p * 8) = *(short8v*)(St + tok * SS + sg * 24 + p * 8);
#pragma unroll
      for (int p = 0; p < 2; ++p)
        *(short8v*)(xgx + gt * 256 + sg * 16 + p * 8) = *(short8v*)(St + tok * SS + 384 + sg * 16 + p * 8);
    }
  }
}

// ---------------------------------------------------------------------------
// Fused scans. Memory scan: all ht-matvecs folded into H^T MFMAs (no htb).
// ---------------------------------------------------------------------------
__global__ __launch_bounds__(512) void scan_k(
    const float* __restrict__ Wf, const float* __restrict__ bf_,
    const float* __restrict__ Wg, const float* __restrict__ Wgg,
    const float* __restrict__ Whh, const float* __restrict__ bhh,
    const float* __restrict__ h0v, const float* __restrict__ m0,
    const ushort* __restrict__ gxb, const ushort* __restrict__ xgx,
    const float* __restrict__ wallb,
    ushort* __restrict__ htsm, ushort* __restrict__ htsg)
{
  const int tid = threadIdx.x;
  const int w = tid >> 6, l = tid & 63, jj = l & 15, seg = l >> 4;

  if (blockIdx.x < 64) {
    // ================= memory scan =================
    const int b = blockIdx.x;
    __shared__ __align__(16) ushort h_bf[32 * 128];  // bf16 h_pre, 16B-rot swizzle
    __shared__ __align__(16) ushort LGb[128];        // bf16 LG (B-frag broadcast)

    const int n0 = w * 16 + seg * 4;   // this lane's 4 output rows / C-frag cols

    // A-frags (bf16):
    short8v afrA[4];   // WfA rows (bigC)
    short8v aggA[4];   // Wg  ht-side rows (G1)
    short8v aggB[4];   // Wgg ht-side rows (G2)
    short8v alg[4];    // WfB rows (lgw)
#pragma unroll
    for (int ks = 0; ks < 4; ++ks) {
      const float* sA = Wf  + (w * 16 + jj) * 256 + ks * 32 + seg * 8;
      const float* sB = Wg  + (w * 16 + jj) * 256 + ks * 32 + seg * 8;
      const float* sC = Wgg + (w * 16 + jj) * 256 + ks * 32 + seg * 8;
      const float* sD = Wf  + (w * 16 + jj) * 256 + 128 + ks * 32 + seg * 8;
      short8v a, bb, c, d;
#pragma unroll
      for (int j = 0; j < 8; ++j) {
        a[j] = (short)f2bf(sA[j]); bb[j] = (short)f2bf(sB[j]);
        c[j] = (short)f2bf(sC[j]); d[j] = (short)f2bf(sD[j]);
      }
      afrA[ks] = a; aggA[ks] = bb; aggB[ks] = c; alg[ks] = d;
    }
    const float4v bf4 = *(const float4v*)(bf_ + n0);

    // init h = m0
    float hreg[2][4];
#pragma unroll
    for (int nt = 0; nt < 2; ++nt) {
      int k = nt * 16 + jj;
      float4v m = *(const float4v*)(m0 + k * 128 + n0);
#pragma unroll
      for (int r = 0; r < 4; ++r) hreg[nt][r] = m[r];
      int p = ((n0 >> 3) + k) & 15;
      short4v pk;
#pragma unroll
      for (int r = 0; r < 4; ++r) pk[r] = (short)f2bf(hreg[nt][r]);
      *(short4v*)(h_bf + k * 128 + p * 8 + (n0 & 7)) = pk;
    }
    const float* wl = wallb + (size_t)b * TT * 32;
    const ushort* xgp = xgx + (size_t)b * TT * 256;
    float wv0 = wl[jj], wv1 = wl[16 + jj];       // w_0  (k = jj / 16+jj)
    float wn0 = wl[32 + jj], wn1 = wl[48 + jj];  // w_1
    short4v xcg  = *(const short4v*)(xgp + n0);          // gain x-side t=0
    short4v xcgg = *(const short4v*)(xgp + 128 + n0);    // gate x-side t=0
    short4v xng  = *(const short4v*)(xgp + 256 + n0);    // t=1
    short4v xngg = *(const short4v*)(xgp + 384 + n0);
    __syncthreads();

    for (int t = 0; t < TT - 1; ++t) {
      // ---- dist-2 global prefetch (never drained by LDS barriers)
      int tw = (t + 2 <= TT - 1) ? (t + 2) : (TT - 1);
      float wf0 = wl[tw * 32 + jj], wf1 = wl[tw * 32 + 16 + jj];
      short4v xfg  = *(const short4v*)(xgp + (size_t)tw * 256 + n0);
      short4v xfgg = *(const short4v*)(xgp + (size_t)tw * 256 + 128 + n0);

      // ---- read h_pre B-frags once
      short8v bv0[4], bv1[4];
#pragma unroll
      for (int ks = 0; ks < 4; ++ks) {
        int g = ks * 4 + seg;
        int p0 = (g + jj) & 15;
        int p1 = (g + 16 + jj) & 15;
        bv0[ks] = *(short8v*)(h_bf + jj * 128 + p0 * 8);
        bv1[ks] = *(short8v*)(h_bf + (16 + jj) * 128 + p1 * 8);
      }

      // ---- H^T MFMAs: bigC (WfA), G1 (Wg), G2 (Wgg)
      float4v acc0 = {0,0,0,0}, acc1 = {0,0,0,0};
      float4v g1a = {0,0,0,0}, g1b = {0,0,0,0};
      float4v g2a = {0,0,0,0}, g2b = {0,0,0,0};
#pragma unroll
      for (int ks = 0; ks < 4; ++ks) {
        acc0 = __builtin_amdgcn_mfma_f32_16x16x32_bf16(afrA[ks], bv0[ks], acc0, 0, 0, 0);
        acc1 = __builtin_amdgcn_mfma_f32_16x16x32_bf16(afrA[ks], bv1[ks], acc1, 0, 0, 0);
        g1a  = __builtin_amdgcn_mfma_f32_16x16x32_bf16(aggA[ks], bv0[ks], g1a, 0, 0, 0);
        g1b  = __builtin_amdgcn_mfma_f32_16x16x32_bf16(aggA[ks], bv1[ks], g1b, 0, 0, 0);
        g2a  = __builtin_amdgcn_mfma_f32_16x16x32_bf16(aggB[ks], bv0[ks], g2a, 0, 0, 0);
        g2b  = __builtin_amdgcn_mfma_f32_16x16x32_bf16(aggB[ks], bv1[ks], g2b, 0, 0, 0);
      }

      // ---- u_g/u_gg = G·w_t via within-wave DPP reduce; LG local
      float lgv[4];
#pragma unroll
      for (int r = 0; r < 4; ++r) {
        float ug  = rsum16(wv0 * g1a[r] + wv1 * g1b[r]) + bf2f((ushort)xcg[r]);
        float ugg = rsum16(wv0 * g2a[r] + wv1 * g2b[r]) + bf2f((ushort)xcgg[r]);
        lgv[r] = tanh_f(ug) * sigm(ugg);
      }
      if (jj == 0) {
        short4v lp;
#pragma unroll
        for (int r = 0; r < 4; ++r) lp[r] = (short)f2bf(lgv[r]);
        *(short4v*)(LGb + n0) = lp;
      }
      bar_lds();  // B1

      // ---- lgw = WfB·LG (broadcast B) -> rows n0+r local
      float4v dlw = {0,0,0,0};
#pragma unroll
      for (int ks = 0; ks < 4; ++ks) {
        short8v blg = *(short8v*)(LGb + ks * 32 + seg * 8);
        dlw = __builtin_amdgcn_mfma_f32_16x16x32_bf16(alg[ks], blg, dlw, 0, 0, 0);
      }

      // ---- epilogue
      float4v htp = {0,0,0,0};
#pragma unroll
      for (int nt = 0; nt < 2; ++nt) {
        float wvv = nt ? wv1 : wv0;
        float wnn = nt ? wn1 : wn0;
        float4v a = nt ? acc1 : acc0;
#pragma unroll
        for (int r = 0; r < 4; ++r) {
          float gam = sigm(a[r] + dlw[r] + bf4[r]);
          float hn = fmaf(gam, hreg[nt][r], wvv * lgv[r]);
          hreg[nt][r] = hn;
          htp[r] = fmaf(wnn, hn, htp[r]);
        }
        int k = nt * 16 + jj;
        int p = ((n0 >> 3) + k) & 15;
        short4v pk;
#pragma unroll
        for (int r = 0; r < 4; ++r) pk[r] = (short)f2bf(hreg[nt][r]);
        *(short4v*)(h_bf + k * 128 + p * 8 + (n0 & 7)) = pk;
      }
#pragma unroll
      for (int r = 0; r < 4; ++r) htp[r] = rsum16(htp[r]);
      if (jj == 0) {
        short4v hp;
#pragma unroll
        for (int r = 0; r < 4; ++r) hp[r] = (short)f2bf(htp[r]);
        *(short4v*)(htsm + ((size_t)b * TT + t) * 128 + n0) = hp;
      }
      wv0 = wn0; wv1 = wn1; wn0 = wf0; wn1 = wf1;
      xcg = xng; xcgg = xngg; xng = xfg; xngg = xfgg;
      bar_lds();  // B2
    }
  } else {
    // ================= GRU =================
    const int b = blockIdx.x - 64;
    __shared__ float gh_l[384];
    __shared__ __align__(16) ushort hbg[128];

    short8v wfr[3][4];
    float4v bfr[3];
#pragma unroll
    for (int i = 0; i < 3; ++i) {
      int Mt = w + i * 8;
#pragma unroll
      for (int ks = 0; ks < 4; ++ks) {
        const float* src = Whh + (Mt * 16 + jj) * 128 + ks * 32 + seg * 8;
        short8v tv;
#pragma unroll
        for (int j = 0; j < 8; ++j) tv[j] = (short)f2bf(src[j]);
        wfr[i][ks] = tv;
      }
      bfr[i] = *(const float4v*)(bhh + Mt * 16 + seg * 4);
    }
    const ushort* gpb = gxb + (size_t)b * TT * 384;
    float hj = 0.f;
    ushort gc0 = 0, gc1 = 0, gc2 = 0, gn0 = 0, gn1 = 0, gn2 = 0;
    if (tid < 128) {
      hj = h0v[tid];
      hbg[tid] = f2bf(hj);
      gc0 = gpb[tid]; gc1 = gpb[128 + tid]; gc2 = gpb[256 + tid];
      gn0 = gpb[384 + tid]; gn1 = gpb[512 + tid]; gn2 = gpb[640 + tid];
    }
    __syncthreads();

    for (int t = 0; t < TT - 1; ++t) {
      ushort gf0 = 0, gf1 = 0, gf2 = 0;
      if (tid < 128) {
        int tf = (t + 2 < TT - 1) ? (t + 2) : (TT - 2);
        const ushort* gp = gpb + (size_t)tf * 384;
        gf0 = gp[tid]; gf1 = gp[128 + tid]; gf2 = gp[256 + tid];
      }
      short8v bfrg[4];
#pragma unroll
      for (int ks = 0; ks < 4; ++ks)
        bfrg[ks] = *(short8v*)(hbg + ks * 32 + seg * 8);
      float4v acc0 = bfr[0], acc1 = bfr[1], acc2 = bfr[2];
#pragma unroll
      for (int ks = 0; ks < 4; ++ks) {
        acc0 = __builtin_amdgcn_mfma_f32_16x16x32_bf16(wfr[0][ks], bfrg[ks], acc0, 0, 0, 0);
        acc1 = __builtin_amdgcn_mfma_f32_16x16x32_bf16(wfr[1][ks], bfrg[ks], acc1, 0, 0, 0);
        acc2 = __builtin_amdgcn_mfma_f32_16x16x32_bf16(wfr[2][ks], bfrg[ks], acc2, 0, 0, 0);
      }
      if (jj == 0) {
        *(float4v*)(gh_l + (w + 0) * 16 + seg * 4) = acc0;
        *(float4v*)(gh_l + (w + 8) * 16 + seg * 4) = acc1;
        *(float4v*)(gh_l + (w + 16) * 16 + seg * 4) = acc2;
      }
      bar_lds();
      if (tid < 128) {
        float r = sigm(bf2f(gc0) + gh_l[tid]);
        float z = sigm(bf2f(gc1) + gh_l[128 + tid]);
        float n = tanh_f(bf2f(gc2) + r * gh_l[256 + tid]);
        hj = fmaf(1.f - z, n, z * hj);
        hbg[tid] = f2bf(hj);
        htsg[((size_t)b * TT + t) * 128 + tid] = f2bf(hj);
      }
      gc0 = gn0; gc1 = gn1; gc2 = gn2;
      gn0 = gf0; gn1 = gf1; gn2 = gf2;
      bar_lds();
    }
  }
}

// ---------------------------------------------------------------------------
__global__ __launch_bounds__(256) void combine_k(
    const ushort* __restrict__ htsg, const ushort* __restrict__ htsm,
    const float* __restrict__ c1b, const float* __restrict__ c2b,
    const float* __restrict__ Wp, const float* __restrict__ Wp1,
    float* __restrict__ out)
{
  const int b = blockIdx.x;
  const int wv = threadIdx.x >> 6;
  const int lane = threadIdx.x & 63;
  const float w0 = Wp[lane], w1 = Wp[64 + lane], w2 = Wp[128 + lane], w3 = Wp[192 + lane];
  const float v0 = Wp1[lane], v1 = Wp1[64 + lane], v2 = Wp1[128 + lane], v3 = Wp1[192 + lane];
  if (threadIdx.x == 0) out[(size_t)b * TT] = 0.f;
  for (int tau = wv; tau < TT - 1; tau += 4) {
    size_t base = ((size_t)b * TT + tau) * 128;
    float hg0 = bf2f(htsg[base + lane]), hg1 = bf2f(htsg[base + 64 + lane]);
    float hm0 = bf2f(htsm[base + lane]), hm1 = bf2f(htsm[base + 64 + lane]);
    float qa = hg0 * w0 + hg1 * w1 + hm0 * w2 + hm1 * w3;
    float qb = hg0 * v0 + hg1 * v1 + hm0 * v2 + hm1 * v3;
#pragma unroll
    for (int m = 1; m < 64; m <<= 1) {
      qa += __shfl_xor(qa, m, 64);
      qb += __shfl_xor(qb, m, 64);
    }
    if (lane == 0) {
      size_t idx = (size_t)b * TT + tau + 1;
      out[idx] = sigm(qa + c1b[idx]) * sigm(qb + c2b[idx]);
    }
  }
}

// ---------------------------------------------------------------------------
extern "C" void kernel_launch(void* const* d_in, const int* in_sizes, int n_in,
                              void* d_out, int out_size, void* d_ws, size_t ws_size,
                              hipStream_t stream) {
  (void)in_sizes; (void)n_in; (void)out_size; (void)ws_size;
  const int* a_data = (const int*)d_in[1];
  const int* e_data = (const int*)d_in[2];
  const float* qm   = (const float*)d_in[4];
  const float* semb = (const float*)d_in[5];
  const float* aemb = (const float*)d_in[6];
  const float* eemb = (const float*)d_in[7];
  const float* W1 = (const float*)d_in[8];   const float* b1 = (const float*)d_in[9];
  const float* W2 = (const float*)d_in[10];  const float* b2 = (const float*)d_in[11];
  const float* W3 = (const float*)d_in[12];  const float* b3 = (const float*)d_in[13];
  const float* key = (const float*)d_in[14];
  const float* Wih = (const float*)d_in[15]; const float* Whh = (const float*)d_in[16];
  const float* bih = (const float*)d_in[17]; const float* bhh = (const float*)d_in[18];
  const float* Wg  = (const float*)d_in[19]; const float* bg  = (const float*)d_in[20];
  const float* Wgg = (const float*)d_in[21]; const float* bgg = (const float*)d_in[22];
  const float* Wf  = (const float*)d_in[23]; const float* bf_ = (const float*)d_in[24];
  const float* Wp  = (const float*)d_in[25]; const float* bp  = (const float*)d_in[26];
  const float* Wp1 = (const float*)d_in[27]; const float* bp1 = (const float*)d_in[28];
  const float* h0v = (const float*)d_in[29]; const float* m0  = (const float*)d_in[30];

  char* ws = (char*)d_ws;
  ushort* gxb  = (ushort*)(ws + 0);
  ushort* xgx  = (ushort*)(ws + 24576000);
  float* wallb = (float*)(ws + 40960000);
  ushort* htsm = (ushort*)(ws + 45056000);
  ushort* htsg = (ushort*)(ws + 53248000);
  float* c1b   = (float*)(ws + 61440000);
  float* c2b   = (float*)(ws + 61568000);
  ushort* wts  = (ushort*)(ws + 61696000);
  float* out = (float*)d_out;

  conv_k<<<dim3(784), dim3(256), 0, stream>>>(W1, W2, W3, Wih, key, Wg, Wgg, wts);
  phase1_k<<<dim3(2048), dim3(256), 0, stream>>>(
      a_data, e_data, qm, semb, aemb, eemb, b1, b2, b3, bih, bg, bgg,
      Wp, bp, Wp1, bp1, wts, gxb, xgx, wallb, c1b, c2b);
  scan_k<<<dim3(128), dim3(512), 0, stream>>>(
      Wf, bf_, Wg, Wgg, Whh, bhh, h0v, m0, gxb, xgx, wallb, htsm, htsg);
  combine_k<<<dim3(64), dim3(256), 0, stream>>>(
      htsg, htsm, c1b, c2b, Wp, Wp1, out);
}

// Round 7
// 1001.061 us; speedup vs baseline: 1.1651x; 1.1651x over previous
//
#include <hip/hip_runtime.h>

#define TT 500
typedef __attribute__((ext_vector_type(8))) short short8v;
typedef __attribute__((ext_vector_type(4))) short short4v;
typedef __attribute__((ext_vector_type(4))) float float4v;
typedef unsigned short ushort;

__device__ __forceinline__ ushort f2bf(float f) {
  union { float f; unsigned u; } v; v.f = f;
  unsigned r = v.u + 0x7FFFu + ((v.u >> 16) & 1u);
  return (ushort)(r >> 16);
}
__device__ __forceinline__ float bf2f(ushort u) {
  union { unsigned u; float f; } v; v.u = ((unsigned)u) << 16;
  return v.f;
}
__device__ __forceinline__ float sigm(float x) {
  return __builtin_amdgcn_rcpf(1.f + __builtin_amdgcn_exp2f(-1.44269504088896341f * x));
}
__device__ __forceinline__ float tanh_f(float x) {
  return 1.f - 2.f * __builtin_amdgcn_rcpf(1.f + __builtin_amdgcn_exp2f(2.88539008177792682f * x));
}
// LDS-only barrier: does NOT drain vmcnt -> global prefetches stay in flight.
__device__ __forceinline__ void bar_lds() {
  asm volatile("s_waitcnt lgkmcnt(0)\ns_barrier" ::: "memory");
}
template <int CTRL>
__device__ __forceinline__ float dppadd(float v) {
  int a = __builtin_amdgcn_update_dpp(0, __builtin_bit_cast(int, v), CTRL, 0xF, 0xF, true);
  return v + __builtin_bit_cast(float, a);
}
__device__ __forceinline__ float rsum16(float v) {  // sum over 16-lane row
  v = dppadd<0xB1>(v);
  v = dppadd<0x4E>(v);
  v = dppadd<0x141>(v);  // row_half_mirror
  v = dppadd<0x140>(v);  // row_mirror
  return v;
}
#define MFMA __builtin_amdgcn_mfma_f32_16x16x32_bf16

// ---------------------------------------------------------------------------
// phase0: weights -> bf16
// ---------------------------------------------------------------------------
__global__ __launch_bounds__(256) void conv_k(
    const float* __restrict__ W1, const float* __restrict__ W2,
    const float* __restrict__ W3, const float* __restrict__ Wih,
    const float* __restrict__ key, const float* __restrict__ Wg,
    const float* __restrict__ Wgg, ushort* __restrict__ wts)
{
  int idx = blockIdx.x * 256 + threadIdx.x;
  if (idx >= 200704) return;
  float v;
  if (idx < 32768)       v = W1[idx];
  else if (idx < 81920)  v = W2[idx - 32768];
  else if (idx < 114688) v = W3[idx - 81920];
  else if (idx < 163840) v = Wih[idx - 114688];
  else if (idx < 167936) v = key[idx - 163840];
  else {
    int j = idx - 167936, o = j >> 7, k = j & 127;
    v = (o < 128) ? Wg[o * 256 + 128 + k] : Wgg[(o - 128) * 256 + 128 + k];
  }
  wts[idx] = f2bf(v);
}

// ---------------------------------------------------------------------------
// phase1: token-parallel precompute. LDS overlaid (Xl|Yl then St) for occupancy.
// ---------------------------------------------------------------------------
#define XS 424
#define SS 648

__global__ __launch_bounds__(256, 4) void phase1_k(
    const int* __restrict__ a_data, const int* __restrict__ e_data,
    const float* __restrict__ qm, const float* __restrict__ semb,
    const float* __restrict__ aemb, const float* __restrict__ eemb,
    const float* __restrict__ b1, const float* __restrict__ b2,
    const float* __restrict__ b3, const float* __restrict__ bih,
    const float* __restrict__ bg, const float* __restrict__ bgg,
    const float* __restrict__ Wp, const float* __restrict__ bp,
    const float* __restrict__ Wp1, const float* __restrict__ bp1,
    const ushort* __restrict__ wts,
    ushort* __restrict__ gxb, ushort* __restrict__ xgx,
    float* __restrict__ wallb, float* __restrict__ c1b, float* __restrict__ c2b)
{
  __shared__ __align__(16) ushort sbuf[13568];
  ushort* Xl = sbuf;
  ushort* Yl = sbuf + 6784;
  ushort* St = sbuf;
  const int tid = threadIdx.x;
  const int b = blockIdx.x >> 5, chunk = blockIdx.x & 31;
  const int t0 = chunk * 16;
  const int NT = (TT - t0 < 16) ? (TT - t0) : 16;
  const ushort* w1b  = wts;
  const ushort* w2b  = wts + 32768;
  const ushort* w3b  = wts + 81920;
  const ushort* wihb = wts + 114688;
  const ushort* keyb = wts + 163840;
  const ushort* wgb  = wts + 167936;

  // ---- stage 0: X via ballot-compressed sparse gather
  {
    const int tok = tid >> 4, l16 = tid & 15;
    const int tsrc = (tok < NT) ? tok : (NT - 1);
    const int gt = b * TT + t0 + tsrc;
    const int e = e_data[gt], a = a_data[gt];
    const float* qrow = qm + (size_t)e * 101;
    float qv[7];
#pragma unroll
    for (int i = 0; i < 7; ++i) {
      int s = l16 + 16 * i;
      qv[i] = (s < 101) ? qrow[s] : 0.f;
    }
    const float* sbase = semb + l16 * 8;
    float4v acc0 = {0,0,0,0}, acc1 = {0,0,0,0};
    float cnt = 0.f;
#pragma unroll
    for (int i = 0; i < 7; ++i) {
      unsigned long long bal = __ballot(qv[i] != 0.f);
      unsigned m = (unsigned)((bal >> (tid & 48)) & 0xFFFFull);
      cnt += (float)__popc(m);
      while (m) {
        int s = 16 * i + __builtin_ctz(m);
        m &= m - 1;
        acc0 += *(const float4v*)(sbase + s * 128);
        acc1 += *(const float4v*)(sbase + s * 128 + 4);
      }
    }
    float inv = 1.f / fmaxf(cnt, 1.f);
    ushort* xr = Xl + tok * XS + l16 * 8;
#pragma unroll
    for (int r = 0; r < 4; ++r) { xr[r] = f2bf(acc0[r] * inv); xr[4 + r] = f2bf(acc1[r] * inv); }
    const float* ee = eemb + (size_t)e * 128 + l16 * 8;
    const float* ae = aemb + a * 128 + l16 * 8;
    ushort* xe = Xl + tok * XS + 128 + l16 * 8;
    ushort* xa = Xl + tok * XS + 256 + l16 * 8;
#pragma unroll
    for (int r = 0; r < 8; ++r) { xe[r] = f2bf(ee[r]); xa[r] = f2bf(ae[r]); }
  }
  __syncthreads();

  const int w = tid >> 6, l = tid & 63, jj = l & 15, seg = l >> 4;

  // ---- c1 (reads Xl e_emb part)
  if (tid < 16) {
    int tau = tid;
    if (tau < NT) {
      const ushort* xr = Xl + tau * XS + 128;
      const float* wv = Wp + 256;
      float a0 = bp[0], a1 = 0.f, a2 = 0.f, a3 = 0.f;
      for (int j = 0; j < 128; j += 4) {
        a0 = fmaf(wv[j],     bf2f(xr[j]),     a0);
        a1 = fmaf(wv[j + 1], bf2f(xr[j + 1]), a1);
        a2 = fmaf(wv[j + 2], bf2f(xr[j + 2]), a2);
        a3 = fmaf(wv[j + 3], bf2f(xr[j + 3]), a3);
      }
      c1b[b * TT + t0 + tau] = (a0 + a1) + (a2 + a3);
    }
  }

  // ---- stage A: Y via MFMA
  short8v ax[12];
#pragma unroll
  for (int i = 0; i < 12; ++i)
    ax[i] = *(short8v*)(Xl + jj * XS + i * 32 + seg * 8);

  for (int T = w; T < 24; T += 4) {
    float4v d = {0,0,0,0};
    float bv;
    if (T < 8) {
      const ushort* Bp = w1b + (T * 16 + jj) * 256 + seg * 8;
      bv = b1[T * 16 + jj];
#pragma unroll
      for (int k = 0; k < 8; ++k)
        d = MFMA(ax[k], *(const short8v*)(Bp + k * 32), d, 0, 0, 0);
    } else if (T < 16) {
      const ushort* Bp = w2b + ((T - 8) * 16 + jj) * 384 + seg * 8;
      bv = b2[(T - 8) * 16 + jj];
#pragma unroll
      for (int k = 0; k < 12; ++k)
        d = MFMA(ax[k], *(const short8v*)(Bp + k * 32), d, 0, 0, 0);
    } else {
      const ushort* Bp = w3b + ((T - 16) * 16 + jj) * 256 + seg * 8;
      bv = b3[(T - 16) * 16 + jj];
#pragma unroll
      for (int k = 0; k < 8; ++k)
        d = MFMA(ax[4 + k], *(const short8v*)(Bp + k * 32), d, 0, 0, 0);
    }
#pragma unroll
    for (int r = 0; r < 4; ++r) {
      float y = d[r] + bv;
      Yl[(seg * 4 + r) * XS + T * 16 + jj] = f2bf(y > 0.f ? y : 0.f);
    }
  }
  __syncthreads();

  // ---- load ay regs + c2 (reads Yl se_data part)
  short8v ay[12];
#pragma unroll
  for (int i = 0; i < 12; ++i)
    ay[i] = *(short8v*)(Yl + jj * XS + i * 32 + seg * 8);

  if (tid < 16) {
    int tau = tid;
    if (tau < NT) {
      const ushort* xr = Yl + tau * XS;
      const float* wv = Wp1 + 256;
      float a0 = bp1[0], a1 = 0.f, a2 = 0.f, a3 = 0.f;
      for (int j = 0; j < 128; j += 4) {
        a0 = fmaf(wv[j],     bf2f(xr[j]),     a0);
        a1 = fmaf(wv[j + 1], bf2f(xr[j + 1]), a1);
        a2 = fmaf(wv[j + 2], bf2f(xr[j + 2]), a2);
        a3 = fmaf(wv[j + 3], bf2f(xr[j + 3]), a3);
      }
      c2b[b * TT + t0 + tau] = (a0 + a1) + (a2 + a3);
    }
  }

  // ---- stage B MFMAs (registers only)
  float4v ds[11];
  int nst = 0;
  for (int T = w; T < 42; T += 4, ++nst) {
    const ushort* Bp; int ai;
    if (T < 24)      { Bp = wihb + (T * 16 + jj) * 128 + seg * 8;        ai = 8; }
    else if (T < 40) { Bp = wgb  + ((T - 24) * 16 + jj) * 128 + seg * 8; ai = 4; }
    else             { Bp = keyb + ((T - 40) * 16 + jj) * 128 + seg * 8; ai = 0; }
    float4v d = {0,0,0,0};
#pragma unroll
    for (int k = 0; k < 4; ++k)
      d = MFMA(ay[ai + k], *(const short8v*)(Bp + k * 32), d, 0, 0, 0);
    ds[nst] = d;
  }
  __syncthreads();   // Xl/Yl dead; St may now overlay

  nst = 0;
  for (int T = w; T < 42; T += 4, ++nst) {
    float4v d = ds[nst];
    if (T < 40) {
      float bv = (T < 24) ? bih[T * 16 + jj]
               : (T < 32) ? bg[(T - 24) * 16 + jj] : bgg[(T - 32) * 16 + jj];
      int col = (T < 24) ? (T * 16 + jj) : (384 + (T - 24) * 16 + jj);
#pragma unroll
      for (int r = 0; r < 4; ++r)
        St[(seg * 4 + r) * SS + col] = f2bf(d[r] + bv);
    } else {
#pragma unroll
      for (int r = 0; r < 4; ++r) {
        int tok = seg * 4 + r;
        if (tok < NT)
          wallb[((size_t)(b * TT + t0 + tok)) * 32 + (T - 40) * 16 + jj] = d[r];
      }
    }
  }
  __syncthreads();

  // ---- coalesced copy-out
  {
    const int tok = tid >> 4, sg = tid & 15;
    if (tok < NT) {
      size_t gt = (size_t)b * TT + t0 + tok;
#pragma unroll
      for (int p = 0; p < 3; ++p)
        *(short8v*)(gxb + gt * 384 + sg * 24 + p * 8) = *(short8v*)(St + tok * SS + sg * 24 + p * 8);
#pragma unroll
      for (int p = 0; p < 2; ++p)
        *(short8v*)(xgx + gt * 256 + sg * 16 + p * 8) = *(short8v*)(St + tok * SS + 384 + sg * 16 + p * 8);
    }
  }
}

// ---------------------------------------------------------------------------
// Fused scans. Mem scan: R5 structure (htb broadcast), split 2-dep MFMA chains,
// reads hoisted after barriers. GRU: register h-update, ONE barrier/step,
// double-buffered hb2 to avoid WAR.
// ---------------------------------------------------------------------------
__global__ __launch_bounds__(512) void scan_k(
    const float* __restrict__ Wf, const float* __restrict__ bf_,
    const float* __restrict__ Wg, const float* __restrict__ Wgg,
    const float* __restrict__ Whh, const float* __restrict__ bhh,
    const float* __restrict__ h0v, const float* __restrict__ m0,
    const ushort* __restrict__ gxb, const ushort* __restrict__ xgx,
    const float* __restrict__ wallb,
    ushort* __restrict__ htsm, ushort* __restrict__ htsg)
{
  const int tid = threadIdx.x;
  const int w = tid >> 6, l = tid & 63, jj = l & 15, seg = l >> 4;
  const int n0 = w * 16 + seg * 4;

  if (blockIdx.x < 64) {
    // ================= memory scan =================
    const int b = blockIdx.x;
    __shared__ __align__(16) ushort h_bf[32 * 128];  // bf16 h_pre, 16B-rot swizzle
    __shared__ __align__(16) ushort htb[128];        // bf16 ht broadcast
    __shared__ __align__(16) ushort LGb[128];        // bf16 LG broadcast

    // A-frags (bf16):
    short8v afrA[4], aggA[4], aggB[4], alg[4];
#pragma unroll
    for (int ks = 0; ks < 4; ++ks) {
      const float* sA = Wf  + (w * 16 + jj) * 256 + ks * 32 + seg * 8;
      const float* sB = Wg  + (w * 16 + jj) * 256 + ks * 32 + seg * 8;
      const float* sC = Wgg + (w * 16 + jj) * 256 + ks * 32 + seg * 8;
      const float* sD = Wf  + (w * 16 + jj) * 256 + 128 + ks * 32 + seg * 8;
      short8v a, bb, c, d;
#pragma unroll
      for (int j = 0; j < 8; ++j) {
        a[j] = (short)f2bf(sA[j]); bb[j] = (short)f2bf(sB[j]);
        c[j] = (short)f2bf(sC[j]); d[j] = (short)f2bf(sD[j]);
      }
      afrA[ks] = a; aggA[ks] = bb; aggB[ks] = c; alg[ks] = d;
    }
    const float4v bf4 = *(const float4v*)(bf_ + n0);

    // init h = m0
    float hreg[2][4];
#pragma unroll
    for (int nt = 0; nt < 2; ++nt) {
      int k = nt * 16 + jj;
      float4v m = *(const float4v*)(m0 + k * 128 + n0);
#pragma unroll
      for (int r = 0; r < 4; ++r) hreg[nt][r] = m[r];
      int p = ((n0 >> 3) + k) & 15;
      short4v pk;
#pragma unroll
      for (int r = 0; r < 4; ++r) pk[r] = (short)f2bf(hreg[nt][r]);
      *(short4v*)(h_bf + k * 128 + p * 8 + (n0 & 7)) = pk;
    }
    const float* wl = wallb + (size_t)b * TT * 32;
    const ushort* xgp = xgx + (size_t)b * TT * 256;
    float wv0 = wl[jj], wv1 = wl[16 + jj];
    float wn0 = wl[32 + jj], wn1 = wl[48 + jj];
    short4v xcg  = *(const short4v*)(xgp + n0);
    short4v xcgg = *(const short4v*)(xgp + 128 + n0);
    short4v xng  = *(const short4v*)(xgp + 256 + n0);
    short4v xngg = *(const short4v*)(xgp + 384 + n0);
    // ht0 -> htb
    {
      float4v htp;
#pragma unroll
      for (int r = 0; r < 4; ++r)
        htp[r] = rsum16(wv0 * hreg[0][r] + wv1 * hreg[1][r]);
      if (jj == 0) {
        short4v hp;
#pragma unroll
        for (int r = 0; r < 4; ++r) hp[r] = (short)f2bf(htp[r]);
        *(short4v*)(htb + n0) = hp;
      }
    }
    __syncthreads();

    for (int t = 0; t < TT - 1; ++t) {
      // ---- dist-2 global prefetch
      int tw = (t + 2 <= TT - 1) ? (t + 2) : (TT - 1);
      float wf0 = wl[tw * 32 + jj], wf1 = wl[tw * 32 + 16 + jj];
      short4v xfg  = *(const short4v*)(xgp + (size_t)tw * 256 + n0);
      short4v xfgg = *(const short4v*)(xgp + (size_t)tw * 256 + 128 + n0);

      // ---- hoisted LDS reads (htb first: it's on the chain)
      short8v hb[4];
#pragma unroll
      for (int ks = 0; ks < 4; ++ks)
        hb[ks] = *(short8v*)(htb + ks * 32 + seg * 8);
      short8v bv0[4], bv1[4];
#pragma unroll
      for (int ks = 0; ks < 4; ++ks) {
        int g = ks * 4 + seg;
        bv0[ks] = *(short8v*)(h_bf + jj * 128 + ((g + jj) & 15) * 8);
        bv1[ks] = *(short8v*)(h_bf + (16 + jj) * 128 + ((g + 16 + jj) & 15) * 8);
      }

      // ---- u_g/u_gg (broadcast-B, 2-dep chains, x-side folded into C-init)
      float4v xg4, xgg4;
#pragma unroll
      for (int r = 0; r < 4; ++r) { xg4[r] = bf2f((ushort)xcg[r]); xgg4[r] = bf2f((ushort)xcgg[r]); }
      float4v dg0 = xg4, dg1 = {0,0,0,0}, gg0 = xgg4, gg1 = {0,0,0,0};
      dg0 = MFMA(aggA[0], hb[0], dg0, 0, 0, 0);
      dg0 = MFMA(aggA[1], hb[1], dg0, 0, 0, 0);
      dg1 = MFMA(aggA[2], hb[2], dg1, 0, 0, 0);
      dg1 = MFMA(aggA[3], hb[3], dg1, 0, 0, 0);
      gg0 = MFMA(aggB[0], hb[0], gg0, 0, 0, 0);
      gg0 = MFMA(aggB[1], hb[1], gg0, 0, 0, 0);
      gg1 = MFMA(aggB[2], hb[2], gg1, 0, 0, 0);
      gg1 = MFMA(aggB[3], hb[3], gg1, 0, 0, 0);

      // ---- bigC (2-dep chains, off the immediate chain)
      float4v a0A = {0,0,0,0}, a0B = {0,0,0,0}, a1A = {0,0,0,0}, a1B = {0,0,0,0};
      a0A = MFMA(afrA[0], bv0[0], a0A, 0, 0, 0);
      a0A = MFMA(afrA[1], bv0[1], a0A, 0, 0, 0);
      a0B = MFMA(afrA[2], bv0[2], a0B, 0, 0, 0);
      a0B = MFMA(afrA[3], bv0[3], a0B, 0, 0, 0);
      a1A = MFMA(afrA[0], bv1[0], a1A, 0, 0, 0);
      a1A = MFMA(afrA[1], bv1[1], a1A, 0, 0, 0);
      a1B = MFMA(afrA[2], bv1[2], a1B, 0, 0, 0);
      a1B = MFMA(afrA[3], bv1[3], a1B, 0, 0, 0);

      // ---- LG
      float lgv[4];
#pragma unroll
      for (int r = 0; r < 4; ++r)
        lgv[r] = tanh_f(dg0[r] + dg1[r]) * sigm(gg0[r] + gg1[r]);
      if (jj == 0) {
        short4v lp;
#pragma unroll
        for (int r = 0; r < 4; ++r) lp[r] = (short)f2bf(lgv[r]);
        *(short4v*)(LGb + n0) = lp;
      }
      bar_lds();  // B1

      // ---- lgw (bf folded into C-init, 2-dep)
      short8v lb[4];
#pragma unroll
      for (int ks = 0; ks < 4; ++ks)
        lb[ks] = *(short8v*)(LGb + ks * 32 + seg * 8);
      float4v dl0 = bf4, dl1 = {0,0,0,0};
      dl0 = MFMA(alg[0], lb[0], dl0, 0, 0, 0);
      dl0 = MFMA(alg[1], lb[1], dl0, 0, 0, 0);
      dl1 = MFMA(alg[2], lb[2], dl1, 0, 0, 0);
      dl1 = MFMA(alg[3], lb[3], dl1, 0, 0, 0);

      // ---- epilogue
      float4v htp = {0,0,0,0};
#pragma unroll
      for (int nt = 0; nt < 2; ++nt) {
        float wvv = nt ? wv1 : wv0;
        float wnn = nt ? wn1 : wn0;
#pragma unroll
        for (int r = 0; r < 4; ++r) {
          float a = nt ? (a1A[r] + a1B[r]) : (a0A[r] + a0B[r]);
          float gam = sigm(a + dl0[r] + dl1[r]);
          float hn = fmaf(gam, hreg[nt][r], wvv * lgv[r]);
          hreg[nt][r] = hn;
          htp[r] = fmaf(wnn, hn, htp[r]);
        }
        int k = nt * 16 + jj;
        int p = ((n0 >> 3) + k) & 15;
        short4v pk;
#pragma unroll
        for (int r = 0; r < 4; ++r) pk[r] = (short)f2bf(hreg[nt][r]);
        *(short4v*)(h_bf + k * 128 + p * 8 + (n0 & 7)) = pk;
      }
#pragma unroll
      for (int r = 0; r < 4; ++r) htp[r] = rsum16(htp[r]);
      if (jj == 0) {
        short4v hp;
#pragma unroll
        for (int r = 0; r < 4; ++r) hp[r] = (short)f2bf(htp[r]);
        *(short4v*)(htb + n0) = hp;
        *(short4v*)(htsm + ((size_t)b * TT + t) * 128 + n0) = hp;
      }
      wv0 = wn0; wv1 = wn1; wn0 = wf0; wn1 = wf1;
      xcg = xng; xcgg = xngg; xng = xfg; xngg = xfgg;
      bar_lds();  // B2
    }
  } else {
    // ================= GRU: register h-update, 1 barrier/step =================
    const int b = blockIdx.x - 64;
    __shared__ __align__(16) ushort hb2[2][128];

    short8v wfr[3][4];
    float4v bfr[3];
#pragma unroll
    for (int i = 0; i < 3; ++i) {
      int Mt = w + i * 8;
#pragma unroll
      for (int ks = 0; ks < 4; ++ks) {
        const float* src = Whh + (Mt * 16 + jj) * 128 + ks * 32 + seg * 8;
        short8v tv;
#pragma unroll
        for (int j = 0; j < 8; ++j) tv[j] = (short)f2bf(src[j]);
        wfr[i][ks] = tv;
      }
      bfr[i] = *(const float4v*)(bhh + Mt * 16 + seg * 4);
    }
    const ushort* gpb = gxb + (size_t)b * TT * 384;
    float4v hj4 = *(const float4v*)(h0v + n0);
    if (jj == 0) {
      short4v hp;
#pragma unroll
      for (int r = 0; r < 4; ++r) hp[r] = (short)f2bf(hj4[r]);
      *(short4v*)(&hb2[0][n0]) = hp;
    }
    // x-gate prefetch (t=0, t=1)
    short4v xr_c = *(const short4v*)(gpb + n0);
    short4v xz_c = *(const short4v*)(gpb + 128 + n0);
    short4v xn_c = *(const short4v*)(gpb + 256 + n0);
    short4v xr_n = *(const short4v*)(gpb + 384 + n0);
    short4v xz_n = *(const short4v*)(gpb + 512 + n0);
    short4v xn_n = *(const short4v*)(gpb + 640 + n0);
    __syncthreads();

    for (int t = 0; t < TT - 1; ++t) {
      int tf = (t + 2 < TT - 1) ? (t + 2) : (TT - 2);
      const ushort* gf = gpb + (size_t)tf * 384;
      short4v xr_f = *(const short4v*)(gf + n0);
      short4v xz_f = *(const short4v*)(gf + 128 + n0);
      short4v xn_f = *(const short4v*)(gf + 256 + n0);

      const ushort* hsrc = hb2[t & 1];
      short8v bfrg[4];
#pragma unroll
      for (int ks = 0; ks < 4; ++ks)
        bfrg[ks] = *(short8v*)(hsrc + ks * 32 + seg * 8);

      float4v a0A = bfr[0], a1A = bfr[1], a2A = bfr[2];
      float4v a0B = {0,0,0,0}, a1B = {0,0,0,0}, a2B = {0,0,0,0};
      a0A = MFMA(wfr[0][0], bfrg[0], a0A, 0, 0, 0);
      a0A = MFMA(wfr[0][1], bfrg[1], a0A, 0, 0, 0);
      a0B = MFMA(wfr[0][2], bfrg[2], a0B, 0, 0, 0);
      a0B = MFMA(wfr[0][3], bfrg[3], a0B, 0, 0, 0);
      a1A = MFMA(wfr[1][0], bfrg[0], a1A, 0, 0, 0);
      a1A = MFMA(wfr[1][1], bfrg[1], a1A, 0, 0, 0);
      a1B = MFMA(wfr[1][2], bfrg[2], a1B, 0, 0, 0);
      a1B = MFMA(wfr[1][3], bfrg[3], a1B, 0, 0, 0);
      a2A = MFMA(wfr[2][0], bfrg[0], a2A, 0, 0, 0);
      a2A = MFMA(wfr[2][1], bfrg[1], a2A, 0, 0, 0);
      a2B = MFMA(wfr[2][2], bfrg[2], a2B, 0, 0, 0);
      a2B = MFMA(wfr[2][3], bfrg[3], a2B, 0, 0, 0);

      // gates for rows n0+r live in this lane (cols duplicated across jj)
      ushort* hdst = (ushort*)hb2[(t + 1) & 1];
      short4v hp;
#pragma unroll
      for (int r = 0; r < 4; ++r) {
        float rr = sigm(bf2f((ushort)xr_c[r]) + a0A[r] + a0B[r]);
        float zz = sigm(bf2f((ushort)xz_c[r]) + a1A[r] + a1B[r]);
        float nn = tanh_f(bf2f((ushort)xn_c[r]) + rr * (a2A[r] + a2B[r]));
        hj4[r] = fmaf(1.f - zz, nn, zz * hj4[r]);
        hp[r] = (short)f2bf(hj4[r]);
      }
      if (jj == 0) {
        *(short4v*)(hdst + n0) = hp;
        *(short4v*)(htsg + ((size_t)b * TT + t) * 128 + n0) = hp;
      }
      xr_c = xr_n; xz_c = xz_n; xn_c = xn_n;
      xr_n = xr_f; xz_n = xz_f; xn_n = xn_f;
      bar_lds();
    }
  }
}

// ---------------------------------------------------------------------------
__global__ __launch_bounds__(256) void combine_k(
    const ushort* __restrict__ htsg, const ushort* __restrict__ htsm,
    const float* __restrict__ c1b, const float* __restrict__ c2b,
    const float* __restrict__ Wp, const float* __restrict__ Wp1,
    float* __restrict__ out)
{
  const int b = blockIdx.x;
  const int wv = threadIdx.x >> 6;
  const int lane = threadIdx.x & 63;
  const float w0 = Wp[lane], w1 = Wp[64 + lane], w2 = Wp[128 + lane], w3 = Wp[192 + lane];
  const float v0 = Wp1[lane], v1 = Wp1[64 + lane], v2 = Wp1[128 + lane], v3 = Wp1[192 + lane];
  if (threadIdx.x == 0) out[(size_t)b * TT] = 0.f;
  for (int tau = wv; tau < TT - 1; tau += 4) {
    size_t base = ((size_t)b * TT + tau) * 128;
    float hg0 = bf2f(htsg[base + lane]), hg1 = bf2f(htsg[base + 64 + lane]);
    float hm0 = bf2f(htsm[base + lane]), hm1 = bf2f(htsm[base + 64 + lane]);
    float qa = hg0 * w0 + hg1 * w1 + hm0 * w2 + hm1 * w3;
    float qb = hg0 * v0 + hg1 * v1 + hm0 * v2 + hm1 * v3;
#pragma unroll
    for (int m = 1; m < 64; m <<= 1) {
      qa += __shfl_xor(qa, m, 64);
      qb += __shfl_xor(qb, m, 64);
    }
    if (lane == 0) {
      size_t idx = (size_t)b * TT + tau + 1;
      out[idx] = sigm(qa + c1b[idx]) * sigm(qb + c2b[idx]);
    }
  }
}

// ---------------------------------------------------------------------------
extern "C" void kernel_launch(void* const* d_in, const int* in_sizes, int n_in,
                              void* d_out, int out_size, void* d_ws, size_t ws_size,
                              hipStream_t stream) {
  (void)in_sizes; (void)n_in; (void)out_size; (void)ws_size;
  const int* a_data = (const int*)d_in[1];
  const int* e_data = (const int*)d_in[2];
  const float* qm   = (const float*)d_in[4];
  const float* semb = (const float*)d_in[5];
  const float* aemb = (const float*)d_in[6];
  const float* eemb = (const float*)d_in[7];
  const float* W1 = (const float*)d_in[8];   const float* b1 = (const float*)d_in[9];
  const float* W2 = (const float*)d_in[10];  const float* b2 = (const float*)d_in[11];
  const float* W3 = (const float*)d_in[12];  const float* b3 = (const float*)d_in[13];
  const float* key = (const float*)d_in[14];
  const float* Wih = (const float*)d_in[15]; const float* Whh = (const float*)d_in[16];
  const float* bih = (const float*)d_in[17]; const float* bhh = (const float*)d_in[18];
  const float* Wg  = (const float*)d_in[19]; const float* bg  = (const float*)d_in[20];
  const float* Wgg = (const float*)d_in[21]; const float* bgg = (const float*)d_in[22];
  const float* Wf  = (const float*)d_in[23]; const float* bf_ = (const float*)d_in[24];
  const float* Wp  = (const float*)d_in[25]; const float* bp  = (const float*)d_in[26];
  const float* Wp1 = (const float*)d_in[27]; const float* bp1 = (const float*)d_in[28];
  const float* h0v = (const float*)d_in[29]; const float* m0  = (const float*)d_in[30];

  char* ws = (char*)d_ws;
  ushort* gxb  = (ushort*)(ws + 0);
  ushort* xgx  = (ushort*)(ws + 24576000);
  float* wallb = (float*)(ws + 40960000);
  ushort* htsm = (ushort*)(ws + 45056000);
  ushort* htsg = (ushort*)(ws + 53248000);
  float* c1b   = (float*)(ws + 61440000);
  float* c2b   = (float*)(ws + 61568000);
  ushort* wts  = (ushort*)(ws + 61696000);
  float* out = (float*)d_out;

  conv_k<<<dim3(784), dim3(256), 0, stream>>>(W1, W2, W3, Wih, key, Wg, Wgg, wts);
  phase1_k<<<dim3(2048), dim3(256), 0, stream>>>(
      a_data, e_data, qm, semb, aemb, eemb, b1, b2, b3, bih, bg, bgg,
      Wp, bp, Wp1, bp1, wts, gxb, xgx, wallb, c1b, c2b);
  scan_k<<<dim3(128), dim3(512), 0, stream>>>(
      Wf, bf_, Wg, Wgg, Whh, bhh, h0v, m0, gxb, xgx, wallb, htsm, htsg);
  combine_k<<<dim3(64), dim3(256), 0, stream>>>(
      htsg, htsm, c1b, c2b, Wp, Wp1, out);
}